// Round 2
// baseline (223.511 us; speedup 1.0000x reference)
//
#include <hip/hip_runtime.h>
#include <cstdint>
#include <cstddef>

#define SEQ   2048
#define HID   2048
#define NHEAD 16
#define HDIM  128
#define NQKV  2560
#define KOFF  2048
#define VOFF  2304
#define SCALE 0.08838834764831845f

typedef __bf16 bf16_t;
typedef __attribute__((ext_vector_type(8))) __bf16 bf16x8;
typedef __attribute__((ext_vector_type(4))) float f32x4;

static __device__ __forceinline__ void gl_lds16(const void* g, void* l) {
  __builtin_amdgcn_global_load_lds((const __attribute__((address_space(1))) void*)g,
                                   (__attribute__((address_space(3))) void*)l, 16, 0, 0);
}

// ---------- fp32 -> bf16 convert (x), 8 elems/thread ----------
__global__ void k_cvt(const float* __restrict__ in, bf16_t* __restrict__ outp) {
  int i = blockIdx.x * blockDim.x + threadIdx.x;
  const float4* p = (const float4*)in;
  float4 a = p[2 * i], b = p[2 * i + 1];
  bf16x8 o;
  o[0] = (bf16_t)a.x; o[1] = (bf16_t)a.y; o[2] = (bf16_t)a.z; o[3] = (bf16_t)a.w;
  o[4] = (bf16_t)b.x; o[5] = (bf16_t)b.y; o[6] = (bf16_t)b.z; o[7] = (bf16_t)b.w;
  ((bf16x8*)outp)[i] = o;
}

// ---------- concat bias (fp32) ----------
__global__ void k_bias(const float* __restrict__ bq, const float* __restrict__ bk,
                       const float* __restrict__ bv, float* __restrict__ bias) {
  int i = blockIdx.x * blockDim.x + threadIdx.x;
  if (i < NQKV) bias[i] = (i < KOFF) ? bq[i] : ((i < VOFF) ? bk[i - KOFF] : bv[i - VOFF]);
}

// ---------- transpose + convert weight: in fp32 [K][N] -> out bf16 [N][K] ----------
__global__ void k_twt(const float* __restrict__ in, bf16_t* __restrict__ outp, int K, int N) {
  __shared__ float t[32][33];
  int x = threadIdx.x, y = threadIdx.y;
  int c0 = blockIdx.x * 32, r0 = blockIdx.y * 32;
#pragma unroll
  for (int j = 0; j < 32; j += 8) t[y + j][x] = in[(size_t)(r0 + y + j) * N + c0 + x];
  __syncthreads();
#pragma unroll
  for (int j = 0; j < 32; j += 8)
    outp[(size_t)(c0 + y + j) * K + r0 + x] = (bf16_t)t[x][y + j];
}

// ---------- bf16 transpose: V cols of QKV [2048][2560] -> Vt [256][2048] ----------
__global__ void k_tv(const bf16_t* __restrict__ QKV, bf16_t* __restrict__ Vt) {
  __shared__ bf16_t t[32][33];
  int x = threadIdx.x, y = threadIdx.y;
  int s0 = blockIdx.x * 32, d0 = blockIdx.y * 32;
#pragma unroll
  for (int j = 0; j < 32; j += 8)
    t[y + j][x] = QKV[(size_t)(s0 + y + j) * NQKV + VOFF + d0 + x];
  __syncthreads();
#pragma unroll
  for (int j = 0; j < 32; j += 8)
    Vt[(size_t)(d0 + y + j) * SEQ + s0 + x] = t[x][y + j];
}

// ---------- m97-style GEMM: C[M,N] = A[M,K] @ Bt[N,K]^T (+bias) ----------
template <int BIAS, typename OUTT>
__global__ __launch_bounds__(256) void k_gemm(const bf16_t* __restrict__ A,
                                              const bf16_t* __restrict__ Bt,
                                              const float* __restrict__ bias,
                                              OUTT* __restrict__ C,
                                              int M, int N, int K) {
  __shared__ __align__(16) bf16_t As[128 * 32];
  __shared__ __align__(16) bf16_t Bs[128 * 32];
  const int tid = threadIdx.x;
  const int l = tid & 63, w = tid >> 6;
  const int lr = l & 15, lg = l >> 4;
  const int m0 = blockIdx.y * 128, n0 = blockIdx.x * 128;
  const int wm = (w >> 1) * 64, wn = (w & 1) * 64;
  f32x4 acc[4][4] = {};
  for (int kt = 0; kt < K; kt += 32) {
#pragma unroll
    for (int t = 0; t < 2; ++t) {
      int c = t * 256 + tid;
      gl_lds16(A + (size_t)(m0 + (c >> 2)) * K + kt + (c & 3) * 8,
               As + (size_t)(t * 256 + w * 64) * 8);
    }
#pragma unroll
    for (int t = 0; t < 2; ++t) {
      int c = t * 256 + tid;
      gl_lds16(Bt + (size_t)(n0 + (c >> 2)) * K + kt + (c & 3) * 8,
               Bs + (size_t)(t * 256 + w * 64) * 8);
    }
    asm volatile("s_waitcnt vmcnt(0)" ::: "memory");
    __syncthreads();
    bf16x8 af[4], bfr[4];
#pragma unroll
    for (int i = 0; i < 4; ++i)
      af[i] = *(const bf16x8*)(As + (wm + i * 16 + lr) * 32 + lg * 8);
#pragma unroll
    for (int i = 0; i < 4; ++i)
      bfr[i] = *(const bf16x8*)(Bs + (wn + i * 16 + lr) * 32 + lg * 8);
#pragma unroll
    for (int mi = 0; mi < 4; ++mi)
#pragma unroll
      for (int ni = 0; ni < 4; ++ni)
        acc[mi][ni] =
            __builtin_amdgcn_mfma_f32_16x16x32_bf16(af[mi], bfr[ni], acc[mi][ni], 0, 0, 0);
    __syncthreads();
  }
#pragma unroll
  for (int mi = 0; mi < 4; ++mi)
#pragma unroll
    for (int ni = 0; ni < 4; ++ni) {
      int col = n0 + wn + ni * 16 + lr;
      float bb = BIAS ? bias[col] : 0.0f;
#pragma unroll
      for (int r = 0; r < 4; ++r) {
        int row = m0 + wm + mi * 16 + lg * 4 + r;
        float v = acc[mi][ni][r] + bb;
        if constexpr (sizeof(OUTT) == 2)
          C[(size_t)row * N + col] = (OUTT)v;
        else
          C[(size_t)row * N + col] = v;
      }
    }
}

// ---------- flash attention, causal, GQA ----------
// grid (16 heads, 32 qblocks); block 256 = 4 waves, each wave 16 q rows.
// KBLK=64. LDS layouts (all 256B rows, 4-bit XOR swizzle slot^=(row&15)):
//   Kl[buf][r=0..63][d slot 0..15]           (logical element (r,d))
//   Vl[buf][R=0..63][slot]  row R holds d=2R,2R+1 : s=(d&1)*8+(k>>3)
//   Pl[wave][q=0..15][64]   stride 128B, 3-bit swizzle slot^=(q&7)
// Staged with global_load_lds (linear LDS dest, pre-swizzled GLOBAL source),
// double-buffered: issue stage(kb+1) before compute(kb), one vmcnt(0)+barrier/tile.
__global__ __launch_bounds__(256) void k_attn(const bf16_t* __restrict__ QKV,
                                              const bf16_t* __restrict__ Vt,
                                              bf16_t* __restrict__ AO) {
  __shared__ __align__(16) bf16_t Kl[2 * 64 * 128];
  __shared__ __align__(16) bf16_t Vl[2 * 64 * 128];
  __shared__ __align__(16) bf16_t Pl[4 * 16 * 64];
  const int h = blockIdx.x;
  const int y = blockIdx.y;
  const int qb = (y < 16) ? (31 - y) : (y - 16);  // pair heavy+light per CU (sum=33)
  const int hkv = h >> 3;
  const int tid = threadIdx.x;
  const int l = tid & 63, w = tid >> 6;
  const int lr = l & 15, lg = l >> 4;
  const int q0 = qb * 64 + w * 16;
  bf16_t* Pw = Pl + w * 16 * 64;

  // Q fragments (A-layout: row=lane&15, k-slot=(lane>>4)*8)
  bf16x8 qf[4];
#pragma unroll
  for (int dt = 0; dt < 4; ++dt)
    qf[dt] = *(const bf16x8*)(QKV + (size_t)(q0 + lr) * NQKV + h * HDIM + dt * 32 + lg * 8);

  f32x4 oa[8] = {};
  float m[4], ls[4];
#pragma unroll
  for (int r = 0; r < 4; ++r) { m[r] = -1e30f; ls[r] = 0.0f; }

  // ---- staging macro: fill buffer b with K/V tile kb (pre-swizzled source) ----
#define STAGE(b, kbv)                                                                   \
  {                                                                                     \
    bf16_t* Kb = Kl + (b) * 8192;                                                       \
    bf16_t* Vb = Vl + (b) * 8192;                                                       \
    _Pragma("unroll") for (int t = 0; t < 4; ++t) {                                     \
      int c = t * 256 + tid;                                                            \
      int r = c >> 4, sp = c & 15, s = sp ^ (r & 15);                                   \
      gl_lds16(QKV + (size_t)((kbv) * 64 + r) * NQKV + KOFF + hkv * HDIM + s * 8,       \
               Kb + (size_t)(t * 256 + w * 64) * 8);                                    \
    }                                                                                   \
    _Pragma("unroll") for (int t = 0; t < 4; ++t) {                                     \
      int c = t * 256 + tid;                                                            \
      int R = c >> 4, sp = c & 15, s = sp ^ (R & 15);                                   \
      int d = R * 2 + (s >> 3), ks = s & 7;                                             \
      gl_lds16(Vt + (size_t)(hkv * HDIM + d) * SEQ + (kbv) * 64 + ks * 8,               \
               Vb + (size_t)(t * 256 + w * 64) * 8);                                    \
    }                                                                                   \
  }

  STAGE(0, 0);
  asm volatile("s_waitcnt vmcnt(0)" ::: "memory");
  __syncthreads();
  int cur = 0;

  for (int kb = 0; kb <= qb; ++kb) {
    if (kb < qb) STAGE(cur ^ 1, kb + 1);
    const bf16_t* Kb = Kl + cur * 8192;
    const bf16_t* Vb = Vl + cur * 8192;

    // scores: S = Q @ K^T * SCALE  (C layout: row q=lg*4+r, col k=ki*16+lr)
    float sc[4][4];
    __builtin_amdgcn_s_setprio(1);
#pragma unroll
    for (int ki = 0; ki < 4; ++ki) {
      f32x4 sa = {};
      int krow = ki * 16 + lr;
#pragma unroll
      for (int dt = 0; dt < 4; ++dt) {
        int slot = (dt * 4 + lg) ^ lr;  // krow&15 == lr
        bf16x8 kf = *(const bf16x8*)(Kb + krow * 128 + slot * 8);
        sa = __builtin_amdgcn_mfma_f32_16x16x32_bf16(qf[dt], kf, sa, 0, 0, 0);
      }
#pragma unroll
      for (int r = 0; r < 4; ++r) {
        float s = sa[r] * SCALE;
        if (kb == qb) {
          int kg = kb * 64 + ki * 16 + lr;
          int qg = q0 + lg * 4 + r;
          if (kg > qg) s = -1e30f;
        }
        sc[ki][r] = s;
      }
    }
    __builtin_amdgcn_s_setprio(0);

    // online softmax (row stats redundant across the 16 lanes of a group)
    float al[4];
#pragma unroll
    for (int r = 0; r < 4; ++r) {
      float tm = fmaxf(fmaxf(sc[0][r], sc[1][r]), fmaxf(sc[2][r], sc[3][r]));
      tm = fmaxf(tm, __shfl_xor(tm, 1));
      tm = fmaxf(tm, __shfl_xor(tm, 2));
      tm = fmaxf(tm, __shfl_xor(tm, 4));
      tm = fmaxf(tm, __shfl_xor(tm, 8));
      float mn = fmaxf(m[r], tm);
      al[r] = __expf(m[r] - mn);
      m[r] = mn;
      float rs = 0.0f;
#pragma unroll
      for (int ki = 0; ki < 4; ++ki) {
        float p = __expf(sc[ki][r] - mn);
        sc[ki][r] = p;
        rs += p;
      }
      rs += __shfl_xor(rs, 1);
      rs += __shfl_xor(rs, 2);
      rs += __shfl_xor(rs, 4);
      rs += __shfl_xor(rs, 8);
      ls[r] = ls[r] * al[r] + rs;
    }
#pragma unroll
    for (int dt = 0; dt < 8; ++dt)
#pragma unroll
      for (int r = 0; r < 4; ++r) oa[dt][r] *= al[r];

    // P (C-layout) -> per-wave LDS (swizzled) -> A-fragment layout
#pragma unroll
    for (int ki = 0; ki < 4; ++ki)
#pragma unroll
      for (int r = 0; r < 4; ++r) {
        int q = lg * 4 + r;
        int slot = (ki * 2 + (lr >> 3)) ^ (q & 7);
        Pw[q * 64 + slot * 8 + (lr & 7)] = (bf16_t)sc[ki][r];
      }
    asm volatile("s_waitcnt lgkmcnt(0)" ::: "memory");
    __builtin_amdgcn_sched_barrier(0);

    // O += P @ V
    __builtin_amdgcn_s_setprio(1);
#pragma unroll
    for (int kk = 0; kk < 2; ++kk) {
      int pslot = (kk * 4 + lg) ^ (lr & 7);
      bf16x8 pf = *(const bf16x8*)(Pw + lr * 64 + pslot * 8);
#pragma unroll
      for (int dt = 0; dt < 8; ++dt) {
        int d = dt * 16 + lr;
        int R = d >> 1;
        int slot = ((d & 1) * 8 + kk * 4 + lg) ^ (R & 15);
        bf16x8 vf = *(const bf16x8*)(Vb + R * 128 + slot * 8);
        oa[dt] = __builtin_amdgcn_mfma_f32_16x16x32_bf16(pf, vf, oa[dt], 0, 0, 0);
      }
    }
    __builtin_amdgcn_s_setprio(0);

    asm volatile("s_waitcnt vmcnt(0)" ::: "memory");
    __syncthreads();
    cur ^= 1;
  }
#undef STAGE

  // epilogue: normalize and store [s][h*128+d] bf16
#pragma unroll
  for (int dt = 0; dt < 8; ++dt)
#pragma unroll
    for (int r = 0; r < 4; ++r) {
      float v = oa[dt][r] / ls[r];
      AO[(size_t)(q0 + lg * 4 + r) * HID + h * HDIM + dt * 16 + lr] = (bf16_t)v;
    }
}

extern "C" void kernel_launch(void* const* d_in, const int* in_sizes, int n_in,
                              void* d_out, int out_size, void* d_ws, size_t ws_size,
                              hipStream_t stream) {
  (void)in_sizes; (void)n_in; (void)out_size; (void)ws_size;
  const float* x  = (const float*)d_in[0];
  const float* Wq = (const float*)d_in[1];
  const float* bq = (const float*)d_in[2];
  const float* Wk = (const float*)d_in[3];
  const float* bk = (const float*)d_in[4];
  const float* Wv = (const float*)d_in[5];
  const float* bv = (const float*)d_in[6];
  const float* Wo = (const float*)d_in[7];
  float* outp = (float*)d_out;

  char* ws = (char*)d_ws;
  const size_t OFF_XB   = 0;                      // [2048][2048] bf16
  const size_t OFF_WQKV = 8388608;                // [2560][2048] bf16 (Wq^T;Wk^T;Wv^T)
  const size_t OFF_WOT  = OFF_WQKV + 10485760;    // [2048][2048] bf16
  const size_t OFF_QKV  = OFF_WOT + 8388608;      // [2048][2560] bf16
  const size_t OFF_VT   = OFF_QKV + 10485760;     // [256][2048] bf16
  const size_t OFF_AO   = OFF_VT + 1048576;       // [2048][2048] bf16
  const size_t OFF_BIAS = OFF_AO + 8388608;       // [2560] fp32
  bf16_t* xb    = (bf16_t*)(ws + OFF_XB);
  bf16_t* WqkvT = (bf16_t*)(ws + OFF_WQKV);
  bf16_t* WoT   = (bf16_t*)(ws + OFF_WOT);
  bf16_t* QKV   = (bf16_t*)(ws + OFF_QKV);
  bf16_t* Vt    = (bf16_t*)(ws + OFF_VT);
  bf16_t* AO    = (bf16_t*)(ws + OFF_AO);
  float*  bias  = (float*)(ws + OFF_BIAS);

  k_cvt<<<2048, 256, 0, stream>>>(x, xb);
  k_bias<<<10, 256, 0, stream>>>(bq, bk, bv, bias);
  k_twt<<<dim3(64, 64), dim3(32, 8), 0, stream>>>(Wq, WqkvT, 2048, 2048);
  k_twt<<<dim3(8, 64), dim3(32, 8), 0, stream>>>(Wk, WqkvT + (size_t)2048 * 2048, 2048, 256);
  k_twt<<<dim3(8, 64), dim3(32, 8), 0, stream>>>(Wv, WqkvT + (size_t)2304 * 2048, 2048, 256);
  k_twt<<<dim3(64, 64), dim3(32, 8), 0, stream>>>(Wo, WoT, 2048, 2048);
  k_gemm<1, bf16_t><<<dim3(20, 16), 256, 0, stream>>>(xb, WqkvT, bias, QKV, 2048, 2560, 2048);
  k_tv<<<dim3(64, 8), dim3(32, 8), 0, stream>>>(QKV, Vt);
  k_attn<<<dim3(16, 32), 256, 0, stream>>>(QKV, Vt, AO);
  k_gemm<0, float><<<dim3(16, 16), 256, 0, stream>>>(AO, WoT, nullptr, outp, 2048, 2048, 2048);
}

// Round 3
// 182.126 us; speedup vs baseline: 1.2272x; 1.2272x over previous
//
#include <hip/hip_runtime.h>
#include <cstdint>
#include <cstddef>

#define SEQ   2048
#define HID   2048
#define NHEAD 16
#define HDIM  128
#define NQKV  2560
#define KOFF  2048
#define VOFF  2304
#define SCALE 0.08838834764831845f

typedef __bf16 bf16_t;
typedef __attribute__((ext_vector_type(8))) __bf16 bf16x8;
typedef __attribute__((ext_vector_type(4))) float f32x4;

static __device__ __forceinline__ void gl_lds16(const void* g, void* l) {
  __builtin_amdgcn_global_load_lds((const __attribute__((address_space(1))) void*)g,
                                   (__attribute__((address_space(3))) void*)l, 16, 0, 0);
}

// ---------- fp32 -> bf16 convert (x), 8 elems/thread ----------
__global__ void k_cvt(const float* __restrict__ in, bf16_t* __restrict__ outp) {
  int i = blockIdx.x * blockDim.x + threadIdx.x;
  const float4* p = (const float4*)in;
  float4 a = p[2 * i], b = p[2 * i + 1];
  bf16x8 o;
  o[0] = (bf16_t)a.x; o[1] = (bf16_t)a.y; o[2] = (bf16_t)a.z; o[3] = (bf16_t)a.w;
  o[4] = (bf16_t)b.x; o[5] = (bf16_t)b.y; o[6] = (bf16_t)b.z; o[7] = (bf16_t)b.w;
  ((bf16x8*)outp)[i] = o;
}

// ---------- concat bias (fp32) ----------
__global__ void k_bias(const float* __restrict__ bq, const float* __restrict__ bk,
                       const float* __restrict__ bv, float* __restrict__ bias) {
  int i = blockIdx.x * blockDim.x + threadIdx.x;
  if (i < NQKV) bias[i] = (i < KOFF) ? bq[i] : ((i < VOFF) ? bk[i - KOFF] : bv[i - VOFF]);
}

// ---------- transpose + convert weight: in fp32 [K][N] -> out bf16 [N][K] ----------
__global__ void k_twt(const float* __restrict__ in, bf16_t* __restrict__ outp, int K, int N) {
  __shared__ float t[32][33];
  int x = threadIdx.x, y = threadIdx.y;
  int c0 = blockIdx.x * 32, r0 = blockIdx.y * 32;
#pragma unroll
  for (int j = 0; j < 32; j += 8) t[y + j][x] = in[(size_t)(r0 + y + j) * N + c0 + x];
  __syncthreads();
#pragma unroll
  for (int j = 0; j < 32; j += 8)
    outp[(size_t)(c0 + y + j) * K + r0 + x] = (bf16_t)t[x][y + j];
}

// ---------- bf16 transpose V -> Vg[d][sigma], sigma interleaved within 32-runs:
// sigma(s) = (s&~31) | ((s&15)<<1) | ((s>>4)&1)
__global__ void k_tv(const bf16_t* __restrict__ QKV, bf16_t* __restrict__ Vg) {
  __shared__ bf16_t t[32][33];
  int x = threadIdx.x, y = threadIdx.y;
  int s0 = blockIdx.x * 32, d0 = blockIdx.y * 32;
#pragma unroll
  for (int j = 0; j < 32; j += 8)
    t[y + j][x] = QKV[(size_t)(s0 + y + j) * NQKV + VOFF + d0 + x];
  __syncthreads();
  int sig = ((x & 15) << 1) | (x >> 4);
#pragma unroll
  for (int j = 0; j < 32; j += 8)
    Vg[(size_t)(d0 + y + j) * SEQ + s0 + sig] = t[x][y + j];
}

// ---------- m97-style GEMM: C[M,N] = A[M,K] @ Bt[N,K]^T (+bias) ----------
template <int BIAS, typename OUTT>
__global__ __launch_bounds__(256) void k_gemm(const bf16_t* __restrict__ A,
                                              const bf16_t* __restrict__ Bt,
                                              const float* __restrict__ bias,
                                              OUTT* __restrict__ C,
                                              int M, int N, int K) {
  __shared__ __align__(16) bf16_t As[128 * 32];
  __shared__ __align__(16) bf16_t Bs[128 * 32];
  const int tid = threadIdx.x;
  const int l = tid & 63, w = tid >> 6;
  const int lr = l & 15, lg = l >> 4;
  const int m0 = blockIdx.y * 128, n0 = blockIdx.x * 128;
  const int wm = (w >> 1) * 64, wn = (w & 1) * 64;
  f32x4 acc[4][4] = {};
  for (int kt = 0; kt < K; kt += 32) {
#pragma unroll
    for (int t = 0; t < 2; ++t) {
      int c = t * 256 + tid;
      gl_lds16(A + (size_t)(m0 + (c >> 2)) * K + kt + (c & 3) * 8,
               As + (size_t)(t * 256 + w * 64) * 8);
    }
#pragma unroll
    for (int t = 0; t < 2; ++t) {
      int c = t * 256 + tid;
      gl_lds16(Bt + (size_t)(n0 + (c >> 2)) * K + kt + (c & 3) * 8,
               Bs + (size_t)(t * 256 + w * 64) * 8);
    }
    asm volatile("s_waitcnt vmcnt(0)" ::: "memory");
    __syncthreads();
    bf16x8 af[4], bfr[4];
#pragma unroll
    for (int i = 0; i < 4; ++i)
      af[i] = *(const bf16x8*)(As + (wm + i * 16 + lr) * 32 + lg * 8);
#pragma unroll
    for (int i = 0; i < 4; ++i)
      bfr[i] = *(const bf16x8*)(Bs + (wn + i * 16 + lr) * 32 + lg * 8);
#pragma unroll
    for (int mi = 0; mi < 4; ++mi)
#pragma unroll
      for (int ni = 0; ni < 4; ++ni)
        acc[mi][ni] =
            __builtin_amdgcn_mfma_f32_16x16x32_bf16(af[mi], bfr[ni], acc[mi][ni], 0, 0, 0);
    __syncthreads();
  }
#pragma unroll
  for (int mi = 0; mi < 4; ++mi)
#pragma unroll
    for (int ni = 0; ni < 4; ++ni) {
      int col = n0 + wn + ni * 16 + lr;
      float bb = BIAS ? bias[col] : 0.0f;
#pragma unroll
      for (int r = 0; r < 4; ++r) {
        int row = m0 + wm + mi * 16 + lg * 4 + r;
        float v = acc[mi][ni][r] + bb;
        if constexpr (sizeof(OUTT) == 2)
          C[(size_t)row * N + col] = (OUTT)v;
        else
          C[(size_t)row * N + col] = v;
      }
    }
}

// ---------- flash attention, causal, GQA — swapped-QK^T, in-register P ----------
// grid (16 heads, 32 qblocks); block 256 = 4 waves, each wave 16 q rows. KVBLK=64.
// QK^T = mfma(K, Q): C[k][q] col=lane&15=q, row=lg*4+reg=k -> P lane-local per q-row.
// PV uses k-slot permutation pi(lg*8+e)=lg*4+(e>>1)+16*(e&1) on BOTH operands:
//   A: pf[e]=sc[2kp+(e&1)][e>>1] (in-register), B: V stored sigma-interleaved so the
//   permuted fragment is one contiguous 16B read.
// LDS: K[64][128] + V[64 rows: d-pair x 64 sigma][128], both 256B rows, XOR-swizzled
// slot^=(row&15), staged via global_load_lds (pre-swizzled global source), dbuf.
__global__ __launch_bounds__(256) void k_attn(const bf16_t* __restrict__ QKV,
                                              const bf16_t* __restrict__ Vg,
                                              bf16_t* __restrict__ AO) {
  __shared__ __align__(16) bf16_t Kl[2 * 64 * 128];
  __shared__ __align__(16) bf16_t Vl[2 * 64 * 128];
  const int h = blockIdx.x;
  const int y = blockIdx.y;
  const int qb = (y < 16) ? (31 - y) : (y - 16);  // pair heavy+light per CU (sum=33)
  const int hkv = h >> 3;
  const int tid = threadIdx.x;
  const int l = tid & 63, w = tid >> 6;
  const int lr = l & 15, lg = l >> 4;
  const int q0 = qb * 64 + w * 16;

  // Q fragments (B-operand: col=lane&15 -> q=lr ; dh-slot=(lane>>4)*8+e)
  bf16x8 qf[4];
#pragma unroll
  for (int dt = 0; dt < 4; ++dt)
    qf[dt] = *(const bf16x8*)(QKV + (size_t)(q0 + lr) * NQKV + h * HDIM + dt * 32 + lg * 8);

  f32x4 oa[8] = {};
  float m = -1e30f, ls = 0.0f;

  // staging source pointers (pre-swizzled global source, linear LDS dest)
  const bf16_t* srcK[4];
  const bf16_t* srcV[4];
#pragma unroll
  for (int t = 0; t < 4; ++t) {
    int c = t * 256 + tid;
    int r = c >> 4, ss = (c & 15) ^ (r & 15);
    srcK[t] = QKV + (size_t)r * NQKV + KOFF + hkv * HDIM + ss * 8;
    srcV[t] = Vg + (size_t)(hkv * HDIM + 2 * r + (ss >> 3)) * SEQ + (ss & 7) * 8;
  }

#define STAGE(b, kbv)                                                        \
  {                                                                          \
    bf16_t* Kb = Kl + (b) * 8192;                                            \
    bf16_t* Vb = Vl + (b) * 8192;                                            \
    _Pragma("unroll") for (int t = 0; t < 4; ++t)                            \
        gl_lds16(srcK[t] + (size_t)(kbv) * 64 * NQKV,                        \
                 Kb + (size_t)(t * 256 + w * 64) * 8);                       \
    _Pragma("unroll") for (int t = 0; t < 4; ++t)                            \
        gl_lds16(srcV[t] + (kbv) * 64, Vb + (size_t)(t * 256 + w * 64) * 8); \
  }

  STAGE(0, 0);
  asm volatile("s_waitcnt vmcnt(0)" ::: "memory");
  __syncthreads();
  int cur = 0;

  for (int kb = 0; kb <= qb; ++kb) {
    if (kb < qb) STAGE(cur ^ 1, kb + 1);
    const bf16_t* Kb = Kl + cur * 8192;
    const bf16_t* Vb = Vl + cur * 8192;

    // S^T = K @ Q^T : lane holds S[k=ki*16+lg*4+r][q=lr]
    float sc[4][4];
#pragma unroll
    for (int ki = 0; ki < 4; ++ki) {
      f32x4 sa = {};
      int krow = ki * 16 + lr;
#pragma unroll
      for (int dt = 0; dt < 4; ++dt) {
        bf16x8 kf = *(const bf16x8*)(Kb + krow * 128 + (((dt * 4 + lg) ^ lr) * 8));
        sa = __builtin_amdgcn_mfma_f32_16x16x32_bf16(kf, qf[dt], sa, 0, 0, 0);
      }
#pragma unroll
      for (int r = 0; r < 4; ++r) {
        float s = sa[r] * SCALE;
        if (kb == qb) {
          int kg = kb * 64 + ki * 16 + lg * 4 + r;
          if (kg > q0 + lr) s = -1e30f;
        }
        sc[ki][r] = s;
      }
    }

    // online softmax for q=lr: in-lane tree over 16 + 2 shfl across lg groups
    float t0 = fmaxf(fmaxf(sc[0][0], sc[0][1]), fmaxf(sc[0][2], sc[0][3]));
    float t1 = fmaxf(fmaxf(sc[1][0], sc[1][1]), fmaxf(sc[1][2], sc[1][3]));
    float t2 = fmaxf(fmaxf(sc[2][0], sc[2][1]), fmaxf(sc[2][2], sc[2][3]));
    float t3 = fmaxf(fmaxf(sc[3][0], sc[3][1]), fmaxf(sc[3][2], sc[3][3]));
    float tm = fmaxf(fmaxf(t0, t1), fmaxf(t2, t3));
    tm = fmaxf(tm, __shfl_xor(tm, 16));
    tm = fmaxf(tm, __shfl_xor(tm, 32));
    float mn = fmaxf(m, tm);
    float al = __expf(m - mn);
    m = mn;
    float rs = 0.0f;
#pragma unroll
    for (int ki = 0; ki < 4; ++ki) {
      float p0 = __expf(sc[ki][0] - mn), p1 = __expf(sc[ki][1] - mn);
      float p2 = __expf(sc[ki][2] - mn), p3 = __expf(sc[ki][3] - mn);
      sc[ki][0] = p0; sc[ki][1] = p1; sc[ki][2] = p2; sc[ki][3] = p3;
      rs += (p0 + p1) + (p2 + p3);
    }
    rs += __shfl_xor(rs, 16);
    rs += __shfl_xor(rs, 32);
    ls = ls * al + rs;

    // broadcast rescale factors to O lanes (O row q = lg*4+r lives at lane col d=lr)
    float a0 = __shfl(al, lg * 4 + 0);
    float a1 = __shfl(al, lg * 4 + 1);
    float a2 = __shfl(al, lg * 4 + 2);
    float a3 = __shfl(al, lg * 4 + 3);
#pragma unroll
    for (int dt = 0; dt < 8; ++dt) {
      oa[dt][0] *= a0; oa[dt][1] *= a1; oa[dt][2] *= a2; oa[dt][3] *= a3;
    }

    // pack P into A-fragments: pf[kp][e] = sc[2kp+(e&1)][e>>1]
    bf16x8 pf[2];
#pragma unroll
    for (int kp = 0; kp < 2; ++kp) {
      pf[kp][0] = (bf16_t)sc[2 * kp][0]; pf[kp][1] = (bf16_t)sc[2 * kp + 1][0];
      pf[kp][2] = (bf16_t)sc[2 * kp][1]; pf[kp][3] = (bf16_t)sc[2 * kp + 1][1];
      pf[kp][4] = (bf16_t)sc[2 * kp][2]; pf[kp][5] = (bf16_t)sc[2 * kp + 1][2];
      pf[kp][6] = (bf16_t)sc[2 * kp][3]; pf[kp][7] = (bf16_t)sc[2 * kp + 1][3];
    }

    // O += P @ V  (C[q][d]: col=lane&15=d, row=lg*4+reg=q)
#pragma unroll
    for (int kp = 0; kp < 2; ++kp)
#pragma unroll
      for (int dt = 0; dt < 8; ++dt) {
        int R = dt * 8 + (lr >> 1);
        int slot = (((lr & 1) * 8 + kp * 4 + lg) ^ (R & 15));
        bf16x8 vf = *(const bf16x8*)(Vb + R * 128 + slot * 8);
        oa[dt] = __builtin_amdgcn_mfma_f32_16x16x32_bf16(pf[kp], vf, oa[dt], 0, 0, 0);
      }

    asm volatile("s_waitcnt vmcnt(0)" ::: "memory");
    __syncthreads();
    cur ^= 1;
  }
#undef STAGE

  // epilogue: normalize and store; lane holds O[q=lg*4+r][d=dt*16+lr]
  float l0 = __shfl(ls, lg * 4 + 0);
  float l1 = __shfl(ls, lg * 4 + 1);
  float l2 = __shfl(ls, lg * 4 + 2);
  float l3 = __shfl(ls, lg * 4 + 3);
  float i0 = 1.0f / l0, i1 = 1.0f / l1, i2 = 1.0f / l2, i3 = 1.0f / l3;
#pragma unroll
  for (int dt = 0; dt < 8; ++dt) {
    int d = h * HDIM + dt * 16 + lr;
    AO[(size_t)(q0 + lg * 4 + 0) * HID + d] = (bf16_t)(oa[dt][0] * i0);
    AO[(size_t)(q0 + lg * 4 + 1) * HID + d] = (bf16_t)(oa[dt][1] * i1);
    AO[(size_t)(q0 + lg * 4 + 2) * HID + d] = (bf16_t)(oa[dt][2] * i2);
    AO[(size_t)(q0 + lg * 4 + 3) * HID + d] = (bf16_t)(oa[dt][3] * i3);
  }
}

extern "C" void kernel_launch(void* const* d_in, const int* in_sizes, int n_in,
                              void* d_out, int out_size, void* d_ws, size_t ws_size,
                              hipStream_t stream) {
  (void)in_sizes; (void)n_in; (void)out_size; (void)ws_size;
  const float* x  = (const float*)d_in[0];
  const float* Wq = (const float*)d_in[1];
  const float* bq = (const float*)d_in[2];
  const float* Wk = (const float*)d_in[3];
  const float* bk = (const float*)d_in[4];
  const float* Wv = (const float*)d_in[5];
  const float* bv = (const float*)d_in[6];
  const float* Wo = (const float*)d_in[7];
  float* outp = (float*)d_out;

  char* ws = (char*)d_ws;
  const size_t OFF_XB   = 0;                      // [2048][2048] bf16
  const size_t OFF_WQKV = 8388608;                // [2560][2048] bf16 (Wq^T;Wk^T;Wv^T)
  const size_t OFF_WOT  = OFF_WQKV + 10485760;    // [2048][2048] bf16
  const size_t OFF_QKV  = OFF_WOT + 8388608;      // [2048][2560] bf16
  const size_t OFF_VT   = OFF_QKV + 10485760;     // [256][2048] bf16 (sigma-interleaved)
  const size_t OFF_AO   = OFF_VT + 1048576;       // [2048][2048] bf16
  const size_t OFF_BIAS = OFF_AO + 8388608;       // [2560] fp32
  bf16_t* xb    = (bf16_t*)(ws + OFF_XB);
  bf16_t* WqkvT = (bf16_t*)(ws + OFF_WQKV);
  bf16_t* WoT   = (bf16_t*)(ws + OFF_WOT);
  bf16_t* QKV   = (bf16_t*)(ws + OFF_QKV);
  bf16_t* Vg    = (bf16_t*)(ws + OFF_VT);
  bf16_t* AO    = (bf16_t*)(ws + OFF_AO);
  float*  bias  = (float*)(ws + OFF_BIAS);

  k_cvt<<<2048, 256, 0, stream>>>(x, xb);
  k_bias<<<10, 256, 0, stream>>>(bq, bk, bv, bias);
  k_twt<<<dim3(64, 64), dim3(32, 8), 0, stream>>>(Wq, WqkvT, 2048, 2048);
  k_twt<<<dim3(8, 64), dim3(32, 8), 0, stream>>>(Wk, WqkvT + (size_t)2048 * 2048, 2048, 256);
  k_twt<<<dim3(8, 64), dim3(32, 8), 0, stream>>>(Wv, WqkvT + (size_t)2304 * 2048, 2048, 256);
  k_twt<<<dim3(64, 64), dim3(32, 8), 0, stream>>>(Wo, WoT, 2048, 2048);
  k_gemm<1, bf16_t><<<dim3(20, 16), 256, 0, stream>>>(xb, WqkvT, bias, QKV, 2048, 2560, 2048);
  k_tv<<<dim3(64, 8), dim3(32, 8), 0, stream>>>(QKV, Vg);
  k_attn<<<dim3(16, 32), 256, 0, stream>>>(QKV, Vg, AO);
  k_gemm<0, float><<<dim3(16, 16), 256, 0, stream>>>(AO, WoT, nullptr, outp, 2048, 2048, 2048);
}